// Round 1
// baseline (525.518 us; speedup 1.0000x reference)
//
#include <hip/hip_runtime.h>

#define BB 512
#define PP 30
#define NN 60
#define SS 14
#define NV 5
#define HID 64
#define HH 32
#define DE 5
#define DO_ 6
#define NT 2
#define NE 3540   // 60*59

// workspace float offsets
#define OFF_U   0
#define OFF_V   (BB*HID*NN)          // 1966080
#define OFF_UK  (2*BB*HID*NN)
#define OFF_VY  (3*BB*HID*NN)
#define OFF_EB  (3*BB*HID*NN + BB*NV*HID)
#define OFF_EBS (OFF_EB + BB*NN*DE)

#define US 65   // padded LDS row stride for U/V/Uk (conflict-free per-lane row reads)

// ---------------- K1: per (b,n) column projections U, V(+b1), Uk, Vy(+b1s) ----------------
__global__ __launch_bounds__(256) void k1_proj(
    const float* __restrict__ x, const float* __restrict__ y,
    const float* __restrict__ fr1_w, const float* __restrict__ fr1_b,
    const float* __restrict__ fr1s_w, const float* __restrict__ fr1s_b,
    float* __restrict__ U, float* __restrict__ V, float* __restrict__ Uk, float* __restrict__ Vy)
{
    __shared__ float xl[PP*NN];          // 1800
    __shared__ float yl[SS*NV];          // 70
    __shared__ float w1l[HID*2*PP];      // 3840
    __shared__ float w1sl[HID*(SS+PP)];  // 2816
    __shared__ float b1l[HID], b1sl[HID];
    int b = blockIdx.x, t = threadIdx.x;
    for (int i = t; i < PP*NN; i += 256) xl[i] = x[b*PP*NN + i];
    for (int i = t; i < SS*NV; i += 256) yl[i] = y[b*SS*NV + i];
    for (int i = t; i < HID*2*PP; i += 256) w1l[i] = fr1_w[i];
    for (int i = t; i < HID*(SS+PP); i += 256) w1sl[i] = fr1s_w[i];
    if (t < HID) { b1l[t] = fr1_b[t]; b1sl[t] = fr1s_b[t]; }
    __syncthreads();

    int n = t & 63, hg = t >> 6;        // wave spans n (x-reads conflict-free, w-reads broadcast)
    if (n < NN) {
        for (int hh = 0; hh < 16; hh++) {
            int h = hg*16 + hh;
            float su = 0.f, sv = 0.f, sk = 0.f;
            #pragma unroll
            for (int p = 0; p < PP; p++) {
                float xv = xl[p*NN + n];
                su += w1l[h*2*PP + p]      * xv;
                sv += w1l[h*2*PP + PP + p] * xv;
                sk += w1sl[h*(SS+PP) + p]  * xv;
            }
            U [(b*HID + h)*NN + n] = su;          // [b][h][n] — coalesced store
            V [(b*HID + h)*NN + n] = sv + b1l[h];
            Uk[(b*HID + h)*NN + n] = sk;
        }
    }
    for (int i = t; i < NV*HID; i += 256) {
        int h = i & 63, v = i >> 6;
        float s = 0.f;
        #pragma unroll
        for (int q = 0; q < SS; q++) s += w1sl[h*(SS+PP) + PP + q] * yl[q*NV + v];
        Vy[b*NV*HID + v*HID + h] = s + b1sl[h];
    }
}

// ---------------- K2: (k,v) MLP -> Ebar_sv ----------------
__global__ __launch_bounds__(256) void k2_sv(
    const float* __restrict__ Uk, const float* __restrict__ Vy,
    const float* __restrict__ w2g, const float* __restrict__ b2g,
    const float* __restrict__ w3g, const float* __restrict__ b3g,
    float* __restrict__ Ebsv)
{
    __shared__ float ukl[NN*US];          // 3900
    __shared__ float vyl[NV*68];          // 340
    __shared__ alignas(16) float w2l[HH*HID]; // 2048
    __shared__ float w3l[DE*HH];
    __shared__ float b2l[HH], b3l[DE];
    __shared__ float ebl[NN*DE];
    int b = blockIdx.x, t = threadIdx.x;
    for (int i = t; i < HID*NN; i += 256) { int h = i/NN, n = i%NN; ukl[n*US + h] = Uk[b*HID*NN + i]; }
    for (int i = t; i < NV*HID; i += 256) { int v = i >> 6, h = i & 63; vyl[v*68 + h] = Vy[b*NV*HID + i]; }
    for (int i = t; i < HH*HID; i += 256) w2l[i] = w2g[i];
    for (int i = t; i < DE*HH; i += 256) w3l[i] = w3g[i];
    if (t < HH) b2l[t] = b2g[t];
    if (t < DE) b3l[t] = b3g[t];
    for (int i = t; i < NN*DE; i += 256) ebl[i] = 0.f;
    __syncthreads();

    for (int task = t; task < NN*NV; task += 256) {
        int k = task / NV, v = task % NV;
        float acc[HH];
        #pragma unroll
        for (int j = 0; j < HH; j++) acc[j] = b2l[j];
        for (int kq = 0; kq < HID/4; kq++) {
            float h1[4];
            #pragma unroll
            for (int q = 0; q < 4; q++)
                h1[q] = fmaxf(ukl[k*US + kq*4 + q] + vyl[v*68 + kq*4 + q], 0.f);
            #pragma unroll
            for (int j = 0; j < HH; j++) {
                const float4 w = *(const float4*)&w2l[j*HID + kq*4];
                acc[j] += w.x*h1[0] + w.y*h1[1] + w.z*h1[2] + w.w*h1[3];
            }
        }
        #pragma unroll
        for (int d = 0; d < DE; d++) {
            float s = b3l[d];
            #pragma unroll
            for (int j = 0; j < HH; j++) s += w3l[d*HH + j] * fmaxf(acc[j], 0.f);
            atomicAdd(&ebl[k*DE + d], fmaxf(s, 0.f));
        }
    }
    __syncthreads();
    for (int i = t; i < NN*DE; i += 256) Ebsv[b*NN*DE + i] = ebl[i];
}

// ---------------- K3: edge MLP (hot) -> Ebar ----------------
__global__ __launch_bounds__(256) void k3_edge(
    const float* __restrict__ U, const float* __restrict__ V,
    const float* __restrict__ w2g, const float* __restrict__ b2g,
    const float* __restrict__ w3g, const float* __restrict__ b3g,
    float* __restrict__ Ebar)
{
    __shared__ float ul[NN*US];           // 3900
    __shared__ float vl[NN*US];           // 3900
    __shared__ alignas(16) float w2l[HH*HID]; // 2048
    __shared__ float w3l[DE*HH];
    __shared__ float b2l[HH], b3l[DE];
    __shared__ float ebl[NN*DE];
    int b = blockIdx.x, t = threadIdx.x;
    for (int i = t; i < HID*NN; i += 256) {
        int h = i/NN, n = i%NN;
        ul[n*US + h] = U[b*HID*NN + i];
        vl[n*US + h] = V[b*HID*NN + i];
    }
    for (int i = t; i < HH*HID; i += 256) w2l[i] = w2g[i];
    for (int i = t; i < DE*HH; i += 256) w3l[i] = w3g[i];
    if (t < HH) b2l[t] = b2g[t];
    if (t < DE) b3l[t] = b3g[t];
    for (int i = t; i < NN*DE; i += 256) ebl[i] = 0.f;
    __syncthreads();

    for (int pr = t; pr < NE/2; pr += 256) {
        int e0 = 2*pr, e1 = e0 + 1;
        int r0 = e0/59, j0 = e0 - 59*r0; int s0 = j0 + (j0 >= r0 ? 1 : 0);
        int r1 = e1/59, j1 = e1 - 59*r1; int s1 = j1 + (j1 >= r1 ? 1 : 0);
        const float* ur0 = &ul[r0*US]; const float* vs0 = &vl[s0*US];
        const float* ur1 = &ul[r1*US]; const float* vs1 = &vl[s1*US];
        float acc0[HH], acc1[HH];
        #pragma unroll
        for (int j = 0; j < HH; j++) { acc0[j] = b2l[j]; acc1[j] = b2l[j]; }
        for (int kq = 0; kq < HID/4; kq++) {
            int k = kq*4;
            float h1a[4], h1b[4];
            #pragma unroll
            for (int q = 0; q < 4; q++) {
                h1a[q] = fmaxf(ur0[k+q] + vs0[k+q], 0.f);
                h1b[q] = fmaxf(ur1[k+q] + vs1[k+q], 0.f);
            }
            #pragma unroll
            for (int j = 0; j < HH; j++) {
                const float4 w = *(const float4*)&w2l[j*HID + k];
                acc0[j] += w.x*h1a[0] + w.y*h1a[1] + w.z*h1a[2] + w.w*h1a[3];
                acc1[j] += w.x*h1b[0] + w.y*h1b[1] + w.z*h1b[2] + w.w*h1b[3];
            }
        }
        #pragma unroll
        for (int d = 0; d < DE; d++) {
            float sa = b3l[d], sb = b3l[d];
            #pragma unroll
            for (int j = 0; j < HH; j++) {
                float w = w3l[d*HH + j];
                sa += w * fmaxf(acc0[j], 0.f);
                sb += w * fmaxf(acc1[j], 0.f);
            }
            atomicAdd(&ebl[r0*DE + d], fmaxf(sa, 0.f));
            atomicAdd(&ebl[r1*DE + d], fmaxf(sb, 0.f));
        }
    }
    __syncthreads();
    for (int i = t; i < NN*DE; i += 256) Ebar[b*NN*DE + i] = ebl[i];
}

// ---------------- K4: node MLP + node-sum + final head ----------------
#define CS 40
__global__ __launch_bounds__(64) void k4_out(
    const float* __restrict__ x, const float* __restrict__ Ebar, const float* __restrict__ Ebsv,
    const float* __restrict__ w1g, const float* __restrict__ b1g,
    const float* __restrict__ w2g, const float* __restrict__ b2g,
    const float* __restrict__ w3g, const float* __restrict__ b3g,
    const float* __restrict__ fcw, const float* __restrict__ fcb,
    float* __restrict__ out)
{
    __shared__ alignas(16) float cl[NN*CS];    // 2400
    __shared__ alignas(16) float w1l[HID*CS];  // 2560
    __shared__ alignas(16) float w2l[HH*HID];  // 2048
    __shared__ float w3l[DO_*HH];
    __shared__ float b1l[HID], b2l[HH], b3l[DO_];
    __shared__ float fcl[NT*DO_], fcbl[NT];
    __shared__ float nsum[DO_];
    int b = blockIdx.x, t = threadIdx.x;
    for (int i = t; i < NN*CS; i += 64) {
        int n = i/CS, c = i%CS;
        float v;
        if (c < PP)          v = x[b*PP*NN + c*NN + n];
        else if (c < PP+DE)  v = Ebar[b*NN*DE + n*DE + (c-PP)];
        else                 v = Ebsv[b*NN*DE + n*DE + (c-PP-DE)];
        cl[i] = v;
    }
    for (int i = t; i < HID*CS; i += 64) w1l[i] = w1g[i];
    for (int i = t; i < HH*HID; i += 64) w2l[i] = w2g[i];
    for (int i = t; i < DO_*HH; i += 64) w3l[i] = w3g[i];
    if (t < HID) b1l[t] = b1g[t];
    if (t < HH)  b2l[t] = b2g[t];
    if (t < DO_) { b3l[t] = b3g[t]; nsum[t] = 0.f; }
    if (t < NT*DO_) fcl[t] = fcw[t];
    if (t < NT) fcbl[t] = fcb[t];
    __syncthreads();

    if (t < NN) {
        alignas(16) float c_[CS];
        #pragma unroll
        for (int q = 0; q < CS/4; q++) *(float4*)&c_[q*4] = *(const float4*)&cl[t*CS + q*4];
        float acc[HH];
        #pragma unroll
        for (int j = 0; j < HH; j++) acc[j] = b2l[j];
        for (int kq = 0; kq < HID/4; kq++) {
            float h1q[4];
            #pragma unroll
            for (int qq = 0; qq < 4; qq++) {
                int k = kq*4 + qq;
                float s = b1l[k];
                #pragma unroll
                for (int cq = 0; cq < CS/4; cq++) {
                    const float4 w = *(const float4*)&w1l[k*CS + cq*4];
                    s += w.x*c_[cq*4] + w.y*c_[cq*4+1] + w.z*c_[cq*4+2] + w.w*c_[cq*4+3];
                }
                h1q[qq] = fmaxf(s, 0.f);
            }
            #pragma unroll
            for (int j = 0; j < HH; j++) {
                const float4 w = *(const float4*)&w2l[j*HID + kq*4];
                acc[j] += w.x*h1q[0] + w.y*h1q[1] + w.z*h1q[2] + w.w*h1q[3];
            }
        }
        #pragma unroll
        for (int d = 0; d < DO_; d++) {
            float s = b3l[d];
            #pragma unroll
            for (int j = 0; j < HH; j++) s += w3l[d*HH + j] * fmaxf(acc[j], 0.f);
            atomicAdd(&nsum[d], fmaxf(s, 0.f));
        }
    }
    __syncthreads();
    if (t < NT) {
        float s = fcbl[t];
        #pragma unroll
        for (int d = 0; d < DO_; d++) s += fcl[t*DO_ + d] * nsum[d];
        out[b*NT + t] = fmaxf(s, 0.f);
    }
}

extern "C" void kernel_launch(void* const* d_in, const int* in_sizes, int n_in,
                              void* d_out, int out_size, void* d_ws, size_t ws_size,
                              hipStream_t stream)
{
    const float* x      = (const float*)d_in[0];
    const float* y      = (const float*)d_in[1];
    const float* fr1_w  = (const float*)d_in[2];  const float* fr1_b  = (const float*)d_in[3];
    const float* fr2_w  = (const float*)d_in[4];  const float* fr2_b  = (const float*)d_in[5];
    const float* fr3_w  = (const float*)d_in[6];  const float* fr3_b  = (const float*)d_in[7];
    const float* fr1s_w = (const float*)d_in[8];  const float* fr1s_b = (const float*)d_in[9];
    const float* fr2s_w = (const float*)d_in[10]; const float* fr2s_b = (const float*)d_in[11];
    const float* fr3s_w = (const float*)d_in[12]; const float* fr3s_b = (const float*)d_in[13];
    const float* fo1_w  = (const float*)d_in[14]; const float* fo1_b  = (const float*)d_in[15];
    const float* fo2_w  = (const float*)d_in[16]; const float* fo2_b  = (const float*)d_in[17];
    const float* fo3_w  = (const float*)d_in[18]; const float* fo3_b  = (const float*)d_in[19];
    const float* fcf_w  = (const float*)d_in[20]; const float* fcf_b  = (const float*)d_in[21];

    float* ws  = (float*)d_ws;
    float* U   = ws + OFF_U;
    float* V   = ws + OFF_V;
    float* Uk  = ws + OFF_UK;
    float* Vy  = ws + OFF_VY;
    float* Eb  = ws + OFF_EB;
    float* Ebs = ws + OFF_EBS;

    hipLaunchKernelGGL(k1_proj, dim3(BB), dim3(256), 0, stream,
                       x, y, fr1_w, fr1_b, fr1s_w, fr1s_b, U, V, Uk, Vy);
    hipLaunchKernelGGL(k2_sv, dim3(BB), dim3(256), 0, stream,
                       Uk, Vy, fr2s_w, fr2s_b, fr3s_w, fr3s_b, Ebs);
    hipLaunchKernelGGL(k3_edge, dim3(BB), dim3(256), 0, stream,
                       U, V, fr2_w, fr2_b, fr3_w, fr3_b, Eb);
    hipLaunchKernelGGL(k4_out, dim3(BB), dim3(64), 0, stream,
                       x, Eb, Ebs, fo1_w, fo1_b, fo2_w, fo2_b, fo3_w, fo3_b, fcf_w, fcf_b,
                       (float*)d_out);
}

// Round 2
// 350.334 us; speedup vs baseline: 1.5000x; 1.5000x over previous
//
#include <hip/hip_runtime.h>

#define BB 512
#define PP 30
#define NN 60
#define SS 14
#define NV 5
#define HID 64
#define HH 32
#define DE 5
#define DO_ 6
#define NT 2
#define NE 3540   // 60*59

// workspace float offsets
#define OFF_U   0
#define OFF_V   (BB*HID*NN)
#define OFF_UK  (2*BB*HID*NN)
#define OFF_VY  (3*BB*HID*NN)
#define OFF_EB  (3*BB*HID*NN + BB*NV*HID)          // size 2*BB*NN*DE (two halves)
#define OFF_EBS (OFF_EB + 2*BB*NN*DE)

#define US 68   // LDS row stride for [n][h] tiles: 68*4B=272B, 16B-aligned rows

// ---------------- K1: per (b,n) column projections U, V(+b1), Uk, Vy(+b1s) ----------------
__global__ __launch_bounds__(256) void k1_proj(
    const float* __restrict__ x, const float* __restrict__ y,
    const float* __restrict__ fr1_w, const float* __restrict__ fr1_b,
    const float* __restrict__ fr1s_w, const float* __restrict__ fr1s_b,
    float* __restrict__ U, float* __restrict__ V, float* __restrict__ Uk, float* __restrict__ Vy)
{
    __shared__ float xl[PP*NN];          // 1800
    __shared__ float yl[SS*NV];          // 70
    __shared__ float w1sl[HID*(SS+PP)];  // for the small Vy loop only
    int b = blockIdx.x, t = threadIdx.x;
    for (int i = t; i < PP*NN; i += 256) xl[i] = x[b*PP*NN + i];
    for (int i = t; i < SS*NV; i += 256) yl[i] = y[b*SS*NV + i];
    for (int i = t; i < HID*(SS+PP); i += 256) w1sl[i] = fr1s_w[i];
    __syncthreads();

    int n = t & 63;
    int hg = __builtin_amdgcn_readfirstlane(t >> 6);   // wave-uniform h-group
    if (n < NN) {
        for (int hh = 0; hh < 16; hh++) {
            int h = hg*16 + hh;                         // uniform -> s_load weights
            float bu = fr1_b[h];
            float su = 0.f, sv = 0.f, sk = 0.f;
            #pragma unroll
            for (int p = 0; p < PP; p++) {
                float xv = xl[p*NN + n];
                su += fr1_w[h*2*PP + p]      * xv;
                sv += fr1_w[h*2*PP + PP + p] * xv;
                sk += fr1s_w[h*(SS+PP) + p]  * xv;
            }
            U [(b*HID + h)*NN + n] = su;
            V [(b*HID + h)*NN + n] = sv + bu;
            Uk[(b*HID + h)*NN + n] = sk;
        }
    }
    for (int i = t; i < NV*HID; i += 256) {
        int h = i & 63, v = i >> 6;
        float s = 0.f;
        #pragma unroll
        for (int q = 0; q < SS; q++) s += w1sl[h*(SS+PP) + PP + q] * yl[q*NV + v];
        Vy[b*NV*HID + v*HID + h] = s + fr1s_b[h];
    }
}

// ---------------- K2: (k,v) MLP -> Ebar_sv ----------------
__global__ __launch_bounds__(256) void k2_sv(
    const float* __restrict__ Uk, const float* __restrict__ Vy,
    const float* __restrict__ w2g, const float* __restrict__ b2g,
    const float* __restrict__ w3g, const float* __restrict__ b3g,
    float* __restrict__ Ebsv)
{
    __shared__ alignas(16) float ukl[NN*US];
    __shared__ alignas(16) float vyl[NV*US];
    __shared__ float ebl[NN*DE];
    int b = blockIdx.x, t = threadIdx.x;
    for (int i = t; i < HID*NN; i += 256) { int h = i/NN, n = i - h*NN; ukl[n*US + h] = Uk[b*HID*NN + i]; }
    for (int i = t; i < NV*HID; i += 256) { int v = i >> 6, h = i & 63; vyl[v*US + h] = Vy[b*NV*HID + i]; }
    for (int i = t; i < NN*DE; i += 256) ebl[i] = 0.f;
    __syncthreads();

    for (int task = t; task < NN*NV; task += 256) {
        int k = task / NV, v = task - k*NV;
        float acc[HH];
        #pragma unroll
        for (int j = 0; j < HH; j++) acc[j] = 0.f;
        for (int kq = 0; kq < HID/4; kq++) {
            float4 u4 = *(const float4*)&ukl[k*US + kq*4];
            float4 y4 = *(const float4*)&vyl[v*US + kq*4];
            float h0 = fmaxf(u4.x + y4.x, 0.f);
            float h1 = fmaxf(u4.y + y4.y, 0.f);
            float h2 = fmaxf(u4.z + y4.z, 0.f);
            float h3 = fmaxf(u4.w + y4.w, 0.f);
            #pragma unroll
            for (int j = 0; j < HH; j++) {
                const float4 w = *(const float4*)&w2g[j*HID + kq*4];   // uniform -> s_load
                acc[j] += w.x*h0 + w.y*h1 + w.z*h2 + w.w*h3;
            }
        }
        #pragma unroll
        for (int j = 0; j < HH; j++) acc[j] = fmaxf(acc[j] + b2g[j], 0.f);
        #pragma unroll
        for (int d = 0; d < DE; d++) {
            float s = b3g[d];
            #pragma unroll
            for (int j = 0; j < HH; j++) s += w3g[d*HH + j] * acc[j];
            atomicAdd(&ebl[k*DE + d], fmaxf(s, 0.f));
        }
    }
    __syncthreads();
    for (int i = t; i < NN*DE; i += 256) Ebsv[b*NN*DE + i] = ebl[i];
}

// ---------------- K3: edge MLP (hot) -> Ebar halves ----------------
// grid = 2*BB; block bh handles tasks [half*900, half*900+900) of batch bh>>1.
// task -> r = task/30, sg = task%30, edges j0 = 2*sg, 2*sg+1 (j0=59 masked).
__global__ __launch_bounds__(256) void k3_edge(
    const float* __restrict__ U, const float* __restrict__ V,
    const float* __restrict__ w2g, const float* __restrict__ b2g,
    const float* __restrict__ w3g, const float* __restrict__ b3g,
    float* __restrict__ Eb)
{
    __shared__ alignas(16) float ul[NN*US];
    __shared__ alignas(16) float vl[NN*US];
    __shared__ float ebl[NN*DE];
    int bh = blockIdx.x;
    int b = bh >> 1, half = bh & 1;
    int t = threadIdx.x;
    for (int i = t; i < HID*NN; i += 256) {
        int h = i/NN, n = i - h*NN;
        ul[n*US + h] = U[b*HID*NN + i];
        vl[n*US + h] = V[b*HID*NN + i];
    }
    for (int i = t; i < NN*DE; i += 256) ebl[i] = 0.f;
    __syncthreads();

    int tend = half*900 + 900;
    for (int task = half*900 + t; task < tend; task += 256) {
        int r  = task / 30;
        int sg = task - r*30;
        int j0a = sg*2, j0b = sg*2 + 1;
        int sa = j0a + (j0a >= r ? 1 : 0);
        int sb = j0b + (j0b >= r ? 1 : 0);
        bool validb = (j0b < 59);
        if (sb > 59) sb = 59;

        float acc0[HH], acc1[HH];
        #pragma unroll
        for (int j = 0; j < HH; j++) { acc0[j] = 0.f; acc1[j] = 0.f; }

        const float* urow = &ul[r*US];
        const float* varow = &vl[sa*US];
        const float* vbrow = &vl[sb*US];
        for (int kq = 0; kq < HID/4; kq++) {
            float4 u4 = *(const float4*)&urow[kq*4];
            float4 va = *(const float4*)&varow[kq*4];
            float4 vb = *(const float4*)&vbrow[kq*4];
            float a0 = fmaxf(u4.x + va.x, 0.f), a1 = fmaxf(u4.y + va.y, 0.f);
            float a2 = fmaxf(u4.z + va.z, 0.f), a3 = fmaxf(u4.w + va.w, 0.f);
            float b0 = fmaxf(u4.x + vb.x, 0.f), b1 = fmaxf(u4.y + vb.y, 0.f);
            float b2 = fmaxf(u4.z + vb.z, 0.f), b3 = fmaxf(u4.w + vb.w, 0.f);
            #pragma unroll
            for (int j = 0; j < HH; j++) {
                const float4 w = *(const float4*)&w2g[j*HID + kq*4];   // uniform -> s_load
                acc0[j] += w.x*a0 + w.y*a1 + w.z*a2 + w.w*a3;
                acc1[j] += w.x*b0 + w.y*b1 + w.z*b2 + w.w*b3;
            }
        }
        // h2 = relu(acc + b2)
        #pragma unroll
        for (int j = 0; j < HH; j++) {
            float bj = b2g[j];
            acc0[j] = fmaxf(acc0[j] + bj, 0.f);
            acc1[j] = fmaxf(acc1[j] + bj, 0.f);
        }
        #pragma unroll
        for (int d = 0; d < DE; d++) {
            float s0 = b3g[d], s1 = b3g[d];
            #pragma unroll
            for (int j = 0; j < HH; j++) {
                float w = w3g[d*HH + j];
                s0 += w * acc0[j];
                s1 += w * acc1[j];
            }
            float es = fmaxf(s0, 0.f) + (validb ? fmaxf(s1, 0.f) : 0.f);
            atomicAdd(&ebl[r*DE + d], es);
        }
    }
    __syncthreads();
    for (int i = t; i < NN*DE; i += 256) Eb[bh*NN*DE + i] = ebl[i];
}

// ---------------- K4: node MLP + node-sum + final head ----------------
#define CS 40
#define CSP 41   // b32 LDS stride (odd -> conflict-free)
#define HSP 67
__global__ __launch_bounds__(256) void k4_out(
    const float* __restrict__ x, const float* __restrict__ Eb, const float* __restrict__ Ebs,
    const float* __restrict__ w1g, const float* __restrict__ b1g,
    const float* __restrict__ w2g, const float* __restrict__ b2g,
    const float* __restrict__ w3g, const float* __restrict__ b3g,
    const float* __restrict__ fcw, const float* __restrict__ fcb,
    float* __restrict__ out)
{
    __shared__ float cl[NN*CSP];       // 2460
    __shared__ float hl[NN*HSP];       // 4020
    __shared__ float pl[NN*4*DO_];     // 1440
    __shared__ float nsum[DO_];
    int b = blockIdx.x, t = threadIdx.x;
    for (int i = t; i < NN*CSP; i += 256) {
        int n = i/CSP, c = i - n*CSP;
        float v = 0.f;
        if (c < PP)            v = x[b*PP*NN + c*NN + n];
        else if (c < PP+DE)    v = Eb[(2*b)*NN*DE + n*DE + (c-PP)] + Eb[(2*b+1)*NN*DE + n*DE + (c-PP)];
        else if (c < PP+2*DE)  v = Ebs[b*NN*DE + n*DE + (c-PP-DE)];
        cl[i] = v;
    }
    if (t < DO_) nsum[t] = 0.f;
    __syncthreads();

    int n = t & 63;
    int rep = __builtin_amdgcn_readfirstlane(t >> 6);  // wave-uniform
    if (n < NN) {
        float c_[CS];
        #pragma unroll
        for (int c = 0; c < CS; c++) c_[c] = cl[n*CSP + c];
        #pragma unroll
        for (int kk = 0; kk < 16; kk++) {
            int k = rep*16 + kk;                        // uniform -> s_load weights
            float s = b1g[k];
            #pragma unroll
            for (int c = 0; c < CS; c++) s += w1g[k*CS + c] * c_[c];
            hl[n*HSP + k] = fmaxf(s, 0.f);
        }
    }
    __syncthreads();
    if (n < NN) {
        float acc[8];
        #pragma unroll
        for (int jj = 0; jj < 8; jj++) acc[jj] = b2g[rep*8 + jj];
        for (int k = 0; k < HID; k++) {
            float h = hl[n*HSP + k];
            #pragma unroll
            for (int jj = 0; jj < 8; jj++) acc[jj] += w2g[(rep*8 + jj)*HID + k] * h;
        }
        #pragma unroll
        for (int d = 0; d < DO_; d++) {
            float s = 0.f;
            #pragma unroll
            for (int jj = 0; jj < 8; jj++) s += w3g[d*HH + rep*8 + jj] * fmaxf(acc[jj], 0.f);
            pl[(n*4 + rep)*DO_ + d] = s;
        }
    }
    __syncthreads();
    if (t < NN) {
        #pragma unroll
        for (int d = 0; d < DO_; d++) {
            float s = b3g[d] + pl[(t*4+0)*DO_+d] + pl[(t*4+1)*DO_+d]
                             + pl[(t*4+2)*DO_+d] + pl[(t*4+3)*DO_+d];
            atomicAdd(&nsum[d], fmaxf(s, 0.f));
        }
    }
    __syncthreads();
    if (t < NT) {
        float s = fcb[t];
        #pragma unroll
        for (int d = 0; d < DO_; d++) s += fcw[t*DO_ + d] * nsum[d];
        out[b*NT + t] = fmaxf(s, 0.f);
    }
}

extern "C" void kernel_launch(void* const* d_in, const int* in_sizes, int n_in,
                              void* d_out, int out_size, void* d_ws, size_t ws_size,
                              hipStream_t stream)
{
    const float* x      = (const float*)d_in[0];
    const float* y      = (const float*)d_in[1];
    const float* fr1_w  = (const float*)d_in[2];  const float* fr1_b  = (const float*)d_in[3];
    const float* fr2_w  = (const float*)d_in[4];  const float* fr2_b  = (const float*)d_in[5];
    const float* fr3_w  = (const float*)d_in[6];  const float* fr3_b  = (const float*)d_in[7];
    const float* fr1s_w = (const float*)d_in[8];  const float* fr1s_b = (const float*)d_in[9];
    const float* fr2s_w = (const float*)d_in[10]; const float* fr2s_b = (const float*)d_in[11];
    const float* fr3s_w = (const float*)d_in[12]; const float* fr3s_b = (const float*)d_in[13];
    const float* fo1_w  = (const float*)d_in[14]; const float* fo1_b  = (const float*)d_in[15];
    const float* fo2_w  = (const float*)d_in[16]; const float* fo2_b  = (const float*)d_in[17];
    const float* fo3_w  = (const float*)d_in[18]; const float* fo3_b  = (const float*)d_in[19];
    const float* fcf_w  = (const float*)d_in[20]; const float* fcf_b  = (const float*)d_in[21];

    float* ws  = (float*)d_ws;
    float* U   = ws + OFF_U;
    float* V   = ws + OFF_V;
    float* Uk  = ws + OFF_UK;
    float* Vy  = ws + OFF_VY;
    float* Eb  = ws + OFF_EB;
    float* Ebs = ws + OFF_EBS;

    hipLaunchKernelGGL(k1_proj, dim3(BB), dim3(256), 0, stream,
                       x, y, fr1_w, fr1_b, fr1s_w, fr1s_b, U, V, Uk, Vy);
    hipLaunchKernelGGL(k2_sv, dim3(BB), dim3(256), 0, stream,
                       Uk, Vy, fr2s_w, fr2s_b, fr3s_w, fr3s_b, Ebs);
    hipLaunchKernelGGL(k3_edge, dim3(2*BB), dim3(256), 0, stream,
                       U, V, fr2_w, fr2_b, fr3_w, fr3_b, Eb);
    hipLaunchKernelGGL(k4_out, dim3(BB), dim3(256), 0, stream,
                       x, Eb, Ebs, fo1_w, fo1_b, fo2_w, fo2_b, fo3_w, fo3_b, fcf_w, fcf_b,
                       (float*)d_out);
}

// Round 6
// 245.435 us; speedup vs baseline: 2.1412x; 1.4274x over previous
//
#include <hip/hip_runtime.h>

#define BB 512
#define PP 30
#define NN 60
#define SS 14
#define NV 5
#define HID 64
#define HH 32
#define DE 5
#define DO_ 6
#define NT 2
#define NE 3540   // 60*59

// workspace float offsets (U/V/Uk now [b][n][h] node-major)
#define OFF_U   0
#define OFF_V   (BB*NN*HID)
#define OFF_UK  (2*BB*NN*HID)
#define OFF_VY  (3*BB*NN*HID)
#define OFF_EB  (3*BB*NN*HID + BB*NV*HID)
#define OFF_EBS (OFF_EB + BB*NN*DE)

#define US 68   // LDS row stride (f32) for node tables: 272B rows, 16B-aligned; stride-4-bank rotation -> <=2-way on b128

typedef __bf16 bf16x8 __attribute__((ext_vector_type(8)));
typedef float  f32x4  __attribute__((ext_vector_type(4)));

// ---------------- K1: per (b,n) projections U, V(+b1), Uk (all [b][n][h]), Vy(+b1s) ----------------
__global__ __launch_bounds__(256) void k1_proj(
    const float* __restrict__ x, const float* __restrict__ y,
    const float* __restrict__ fr1_w, const float* __restrict__ fr1_b,
    const float* __restrict__ fr1s_w, const float* __restrict__ fr1s_b,
    float* __restrict__ U, float* __restrict__ V, float* __restrict__ Uk, float* __restrict__ Vy)
{
    __shared__ float xl[PP*NN];   // 1800
    __shared__ float yl[SS*NV];   // 70
    int b = blockIdx.x, t = threadIdx.x;
    for (int i = t; i < PP*NN; i += 256) xl[i] = x[b*PP*NN + i];
    for (int i = t; i < SS*NV; i += 256) yl[i] = y[b*SS*NV + i];

    int h = t & 63, w = t >> 6;     // lane = output channel h (coalesced stores)
    float wu[PP], wv[PP], wk[PP];
    #pragma unroll
    for (int p = 0; p < PP; p++) {
        wu[p] = fr1_w[h*2*PP + p];
        wv[p] = fr1_w[h*2*PP + PP + p];
        wk[p] = fr1s_w[h*(SS+PP) + p];
    }
    float b1h = fr1_b[h];
    __syncthreads();

    for (int n = w*15; n < w*15 + 15; n++) {
        float su = 0.f, sv = 0.f, sk = 0.f;
        #pragma unroll
        for (int p = 0; p < PP; p++) {
            float xv = xl[p*NN + n];      // wave-uniform broadcast
            su += wu[p]*xv; sv += wv[p]*xv; sk += wk[p]*xv;
        }
        U [b*NN*HID + n*HID + h] = su;
        V [b*NN*HID + n*HID + h] = sv + b1h;
        Uk[b*NN*HID + n*HID + h] = sk;
    }
    if (w == 0) {
        float wy[SS];
        #pragma unroll
        for (int q = 0; q < SS; q++) wy[q] = fr1s_w[h*(SS+PP) + PP + q];
        float b1s = fr1s_b[h];
        #pragma unroll
        for (int v = 0; v < NV; v++) {
            float s = 0.f;
            #pragma unroll
            for (int q = 0; q < SS; q++) s += wy[q] * yl[q*NV + v];
            Vy[b*NV*HID + v*HID + h] = s + b1s;
        }
    }
}

// ---------------- fused edge kernel: MFMA layer-2, shfl layer-3, LDS-atomic reduce ----------------
template<int MODE>
__device__ __forceinline__ void edge_impl(
    const float* __restrict__ Usrc, const float* __restrict__ Vsrc,
    const float* __restrict__ w2p, const float* __restrict__ b2p,
    const float* __restrict__ w3p, const float* __restrict__ b3p,
    float* __restrict__ outp, float* uTab, float* vTab, float* ebl, int b)
{
    constexpr int DIV    = MODE ? NV : (NN-1);
    constexpr int NEDGE  = MODE ? NN*NV : NE;
    constexpr int NTILE  = (NEDGE + 15) / 16;
    constexpr int VROWS4 = MODE ? (NV*HID/4) : (NN*HID/4);

    int t = threadIdx.x;
    // stage node tables (f32) into padded LDS
    for (int i4 = t; i4 < NN*HID/4; i4 += 256) {
        int n = i4 >> 4, c4 = i4 & 15;
        *(float4*)&uTab[n*US + c4*4] = ((const float4*)Usrc)[b*(NN*HID/4) + i4];
    }
    for (int i4 = t; i4 < VROWS4; i4 += 256) {
        int n = i4 >> 4, c4 = i4 & 15;
        *(float4*)&vTab[n*US + c4*4] = ((const float4*)Vsrc)[b*VROWS4 + i4];
    }
    for (int i = t; i < NN*8; i += 256) ebl[i] = 0.f;

    int l = t & 63, l15 = l & 15, g = l >> 4;

    // A-frags: W2 rows (swapped GEMM: A = W2 [j][k]); per lane j = mt*16 + l15
    bf16x8 af[2][2];
    #pragma unroll
    for (int mt = 0; mt < 2; mt++)
    #pragma unroll
    for (int kh = 0; kh < 2; kh++) {
        const float* p = &w2p[(mt*16 + l15)*HID + kh*32 + g*8];
        float4 a = *(const float4*)p;
        float4 c = *(const float4*)(p + 4);
        bf16x8 f;
        f[0]=(__bf16)a.x; f[1]=(__bf16)a.y; f[2]=(__bf16)a.z; f[3]=(__bf16)a.w;
        f[4]=(__bf16)c.x; f[5]=(__bf16)c.y; f[6]=(__bf16)c.z; f[7]=(__bf16)c.w;
        af[mt][kh] = f;
    }
    // per-lane j values after MFMA: j = mt*16 + g*4 + q  (D: row=(l>>4)*4+reg, col=edge)
    float b2r[2][4], w3r[5][2][4];
    #pragma unroll
    for (int mt = 0; mt < 2; mt++)
    #pragma unroll
    for (int q = 0; q < 4; q++) {
        int j = mt*16 + g*4 + q;
        b2r[mt][q] = b2p[j];
        #pragma unroll
        for (int d = 0; d < 5; d++) w3r[d][mt][q] = w3p[d*HH + j];
    }
    float b3r[5];
    #pragma unroll
    for (int d = 0; d < 5; d++) b3r[d] = b3p[d];

    __syncthreads();

    int w = t >> 6;
    for (int tile = w; tile < NTILE; tile += 4) {
        int e  = tile*16 + l15;
        int eg = e < NEDGE ? e : NEDGE-1;
        unsigned r = (unsigned)eg / DIV;          // compile-time divisor -> magic mul
        int i  = eg - (int)r*DIV;
        int s  = MODE ? i : (i + (i >= (int)r ? 1 : 0));
        const float* ur = &uTab[r*US];
        const float* vr = &vTab[s*US];

        f32x4 acc0 = {0.f,0.f,0.f,0.f}, acc1 = {0.f,0.f,0.f,0.f};
        #pragma unroll
        for (int kh = 0; kh < 2; kh++) {
            int k0 = kh*32 + g*8;
            float4 ua = *(const float4*)&ur[k0];
            float4 ub = *(const float4*)&ur[k0 + 4];
            float4 va = *(const float4*)&vr[k0];
            float4 vb = *(const float4*)&vr[k0 + 4];
            bf16x8 bf;
            bf[0]=(__bf16)fmaxf(ua.x+va.x,0.f); bf[1]=(__bf16)fmaxf(ua.y+va.y,0.f);
            bf[2]=(__bf16)fmaxf(ua.z+va.z,0.f); bf[3]=(__bf16)fmaxf(ua.w+va.w,0.f);
            bf[4]=(__bf16)fmaxf(ub.x+vb.x,0.f); bf[5]=(__bf16)fmaxf(ub.y+vb.y,0.f);
            bf[6]=(__bf16)fmaxf(ub.z+vb.z,0.f); bf[7]=(__bf16)fmaxf(ub.w+vb.w,0.f);
            acc0 = __builtin_amdgcn_mfma_f32_16x16x32_bf16(af[0][kh], bf, acc0, 0, 0, 0);
            acc1 = __builtin_amdgcn_mfma_f32_16x16x32_bf16(af[1][kh], bf, acc1, 0, 0, 0);
        }
        // layer-3 partials over this lane's 8 j's
        float h2[2][4];
        #pragma unroll
        for (int q = 0; q < 4; q++) {
            h2[0][q] = fmaxf(acc0[q] + b2r[0][q], 0.f);
            h2[1][q] = fmaxf(acc1[q] + b2r[1][q], 0.f);
        }
        float part[5];
        #pragma unroll
        for (int d = 0; d < 5; d++) {
            float s5 = 0.f;
            #pragma unroll
            for (int mt = 0; mt < 2; mt++)
            #pragma unroll
            for (int q = 0; q < 4; q++) s5 += w3r[d][mt][q] * h2[mt][q];
            part[d] = s5;
        }
        // reduce over the 4 lane-groups (j-subsets)
        #pragma unroll
        for (int d = 0; d < 5; d++) {
            part[d] += __shfl_xor(part[d], 16);
            part[d] += __shfl_xor(part[d], 32);
        }
        bool valid = e < NEDGE;
        float val0 = valid ? fmaxf(part[0] + b3r[0], 0.f) : 0.f;
        float val1 = valid ? fmaxf(part[1] + b3r[1], 0.f) : 0.f;
        float val2 = valid ? fmaxf(part[2] + b3r[2], 0.f) : 0.f;
        float val3 = valid ? fmaxf(part[3] + b3r[3], 0.f) : 0.f;
        float val4 = valid ? fmaxf(part[4] + b3r[4], 0.f) : 0.f;
        float vs = (g == 0) ? val0 : (g == 1) ? val1 : (g == 2) ? val2 : val3;
        atomicAdd(&ebl[r*8 + g], vs);
        if (g == 0) atomicAdd(&ebl[r*8 + 4], val4);
    }
    __syncthreads();
    for (int i = t; i < NN*DE; i += 256) {
        int n = i / DE, d = i - n*DE;
        outp[b*NN*DE + i] = ebl[n*8 + d];
    }
}

__global__ __launch_bounds__(256) void k_edge(
    const float* __restrict__ U, const float* __restrict__ V,
    const float* __restrict__ Uk, const float* __restrict__ Vy,
    const float* __restrict__ w2,  const float* __restrict__ b2,
    const float* __restrict__ w3,  const float* __restrict__ b3,
    const float* __restrict__ w2s, const float* __restrict__ b2s,
    const float* __restrict__ w3s, const float* __restrict__ b3s,
    float* __restrict__ Eb, float* __restrict__ Ebs)
{
    __shared__ float uTab[NN*US];
    __shared__ float vTab[NN*US];
    __shared__ float ebl[NN*8];
    if (blockIdx.x < BB)
        edge_impl<0>(U, V, w2, b2, w3, b3, Eb, uTab, vTab, ebl, blockIdx.x);
    else
        edge_impl<1>(Uk, Vy, w2s, b2s, w3s, b3s, Ebs, uTab, vTab, ebl, blockIdx.x - BB);
}

// ---------------- K4: node MLP + node-sum + final head ----------------
#define CS 40
#define CSP 41
#define HSP 67
__global__ __launch_bounds__(256) void k4_out(
    const float* __restrict__ x, const float* __restrict__ Eb, const float* __restrict__ Ebs,
    const float* __restrict__ w1g, const float* __restrict__ b1g,
    const float* __restrict__ w2g, const float* __restrict__ b2g,
    const float* __restrict__ w3g, const float* __restrict__ b3g,
    const float* __restrict__ fcw, const float* __restrict__ fcb,
    float* __restrict__ out)
{
    __shared__ float cl[NN*CSP];
    __shared__ float hl[NN*HSP];
    __shared__ float pl[NN*4*DO_];
    __shared__ float nsum[DO_];
    int b = blockIdx.x, t = threadIdx.x;
    for (int i = t; i < NN*CSP; i += 256) {
        int n = i/CSP, c = i - n*CSP;
        float v = 0.f;
        if (c < PP)            v = x[b*PP*NN + c*NN + n];
        else if (c < PP+DE)    v = Eb[b*NN*DE + n*DE + (c-PP)];
        else if (c < PP+2*DE)  v = Ebs[b*NN*DE + n*DE + (c-PP-DE)];
        cl[i] = v;
    }
    if (t < DO_) nsum[t] = 0.f;
    __syncthreads();

    int n = t & 63;
    int rep = __builtin_amdgcn_readfirstlane(t >> 6);
    if (n < NN) {
        float c_[CS];
        #pragma unroll
        for (int c = 0; c < CS; c++) c_[c] = cl[n*CSP + c];
        #pragma unroll
        for (int kk = 0; kk < 16; kk++) {
            int k = rep*16 + kk;
            float s = b1g[k];
            #pragma unroll
            for (int c = 0; c < CS; c++) s += w1g[k*CS + c] * c_[c];
            hl[n*HSP + k] = fmaxf(s, 0.f);
        }
    }
    __syncthreads();
    if (n < NN) {
        float acc[8];
        #pragma unroll
        for (int jj = 0; jj < 8; jj++) acc[jj] = b2g[rep*8 + jj];
        for (int k = 0; k < HID; k++) {
            float h = hl[n*HSP + k];
            #pragma unroll
            for (int jj = 0; jj < 8; jj++) acc[jj] += w2g[(rep*8 + jj)*HID + k] * h;
        }
        #pragma unroll
        for (int d = 0; d < DO_; d++) {
            float s = 0.f;
            #pragma unroll
            for (int jj = 0; jj < 8; jj++) s += w3g[d*HH + rep*8 + jj] * fmaxf(acc[jj], 0.f);
            pl[(n*4 + rep)*DO_ + d] = s;
        }
    }
    __syncthreads();
    if (t < NN) {
        #pragma unroll
        for (int d = 0; d < DO_; d++) {
            float s = b3g[d] + pl[(t*4+0)*DO_+d] + pl[(t*4+1)*DO_+d]
                             + pl[(t*4+2)*DO_+d] + pl[(t*4+3)*DO_+d];
            atomicAdd(&nsum[d], fmaxf(s, 0.f));
        }
    }
    __syncthreads();
    if (t < NT) {
        float s = fcb[t];
        #pragma unroll
        for (int d = 0; d < DO_; d++) s += fcw[t*DO_ + d] * nsum[d];
        out[b*NT + t] = fmaxf(s, 0.f);
    }
}

extern "C" void kernel_launch(void* const* d_in, const int* in_sizes, int n_in,
                              void* d_out, int out_size, void* d_ws, size_t ws_size,
                              hipStream_t stream)
{
    const float* x      = (const float*)d_in[0];
    const float* y      = (const float*)d_in[1];
    const float* fr1_w  = (const float*)d_in[2];  const float* fr1_b  = (const float*)d_in[3];
    const float* fr2_w  = (const float*)d_in[4];  const float* fr2_b  = (const float*)d_in[5];
    const float* fr3_w  = (const float*)d_in[6];  const float* fr3_b  = (const float*)d_in[7];
    const float* fr1s_w = (const float*)d_in[8];  const float* fr1s_b = (const float*)d_in[9];
    const float* fr2s_w = (const float*)d_in[10]; const float* fr2s_b = (const float*)d_in[11];
    const float* fr3s_w = (const float*)d_in[12]; const float* fr3s_b = (const float*)d_in[13];
    const float* fo1_w  = (const float*)d_in[14]; const float* fo1_b  = (const float*)d_in[15];
    const float* fo2_w  = (const float*)d_in[16]; const float* fo2_b  = (const float*)d_in[17];
    const float* fo3_w  = (const float*)d_in[18]; const float* fo3_b  = (const float*)d_in[19];
    const float* fcf_w  = (const float*)d_in[20]; const float* fcf_b  = (const float*)d_in[21];

    float* ws  = (float*)d_ws;
    float* U   = ws + OFF_U;
    float* V   = ws + OFF_V;
    float* Uk  = ws + OFF_UK;
    float* Vy  = ws + OFF_VY;
    float* Eb  = ws + OFF_EB;
    float* Ebs = ws + OFF_EBS;

    hipLaunchKernelGGL(k1_proj, dim3(BB), dim3(256), 0, stream,
                       x, y, fr1_w, fr1_b, fr1s_w, fr1s_b, U, V, Uk, Vy);
    hipLaunchKernelGGL(k_edge, dim3(2*BB), dim3(256), 0, stream,
                       U, V, Uk, Vy, fr2_w, fr2_b, fr3_w, fr3_b,
                       fr2s_w, fr2s_b, fr3s_w, fr3s_b, Eb, Ebs);
    hipLaunchKernelGGL(k4_out, dim3(BB), dim3(256), 0, stream,
                       x, Eb, Ebs, fo1_w, fo1_b, fo2_w, fo2_b, fo3_w, fo3_b, fcf_w, fcf_b,
                       (float*)d_out);
}

// Round 7
// 180.920 us; speedup vs baseline: 2.9047x; 1.3566x over previous
//
#include <hip/hip_runtime.h>

#define BB 512
#define PP 30
#define NN 60
#define SS 14
#define NV 5
#define HID 64
#define HH 32
#define DE 5
#define DO_ 6
#define NT 2

// workspace float offsets (U/V/Uk are [b][n][h] node-major)
#define OFF_U   0
#define OFF_V   (BB*NN*HID)
#define OFF_UK  (2*BB*NN*HID)
#define OFF_VY  (3*BB*NN*HID)
#define OFF_EB  (3*BB*NN*HID + BB*NV*HID)
#define OFF_EBS (OFF_EB + BB*NN*DE)

#define US 68   // LDS row stride (f32): 272B rows, 16B-aligned

typedef __bf16 bf16x8 __attribute__((ext_vector_type(8)));
typedef float  f32x16 __attribute__((ext_vector_type(16)));

// ---------------- K1: projections U, V(+b1), Uk (all [b][n][h]), Vy(+b1s) ----------------
__global__ __launch_bounds__(256) void k1_proj(
    const float* __restrict__ x, const float* __restrict__ y,
    const float* __restrict__ fr1_w, const float* __restrict__ fr1_b,
    const float* __restrict__ fr1s_w, const float* __restrict__ fr1s_b,
    float* __restrict__ U, float* __restrict__ V, float* __restrict__ Uk, float* __restrict__ Vy)
{
    __shared__ float xl[PP*NN];       // 1800
    __shared__ float yl[SS*NV];       // 70
    __shared__ float w1l[HID*61];     // rows padded 60->61 (bank-free per-lane reads)
    __shared__ float w1sl[HID*45];    // rows padded 44->45
    int b = blockIdx.x, t = threadIdx.x;
    for (int i = t; i < PP*NN; i += 256) xl[i] = x[b*PP*NN + i];
    for (int i = t; i < SS*NV; i += 256) yl[i] = y[b*SS*NV + i];
    for (int i = t; i < HID*2*PP; i += 256) w1l[(i/60)*61 + i%60] = fr1_w[i];
    for (int i = t; i < HID*(SS+PP); i += 256) w1sl[(i/44)*45 + i%44] = fr1s_w[i];
    __syncthreads();

    int h = t & 63, w = t >> 6;
    float wu[PP], wv[PP], wk[PP];
    #pragma unroll
    for (int p = 0; p < PP; p++) {
        wu[p] = w1l[h*61 + p];
        wv[p] = w1l[h*61 + PP + p];
        wk[p] = w1sl[h*45 + p];
    }
    float b1h = fr1_b[h];

    for (int n = w*15; n < w*15 + 15; n++) {
        float su = 0.f, sv = 0.f, sk = 0.f;
        #pragma unroll
        for (int p = 0; p < PP; p++) {
            float xv = xl[p*NN + n];      // wave-uniform broadcast
            su += wu[p]*xv; sv += wv[p]*xv; sk += wk[p]*xv;
        }
        U [b*NN*HID + n*HID + h] = su;
        V [b*NN*HID + n*HID + h] = sv + b1h;
        Uk[b*NN*HID + n*HID + h] = sk;
    }
    if (w == 0) {
        float wy[SS];
        #pragma unroll
        for (int q = 0; q < SS; q++) wy[q] = w1sl[h*45 + PP + q];
        float b1s = fr1s_b[h];
        #pragma unroll
        for (int v = 0; v < NV; v++) {
            float s = 0.f;
            #pragma unroll
            for (int q = 0; q < SS; q++) s += wy[q] * yl[q*NV + v];
            Vy[b*NV*HID + v*HID + h] = s + b1s;
        }
    }
}

// ---------------- edge tile: 32 edges, layer2 (4 MFMA) + layer3 (2 MFMA) ----------------
// A1 layout (32x32x16): row=lane&31, k=(lane>>5)*8+reg.  D: col=lane&31, row=(q&3)+8*(q>>2)+4p.
// D1 reg q holds j=(q&3)+8*(q>>2)+4p for edge el -> B2 halves are regs 0..7 / 8..15.
__device__ __forceinline__ void edge_tile_compute(
    const float* __restrict__ ur, const float* __restrict__ vr,
    const bf16x8* af, const bf16x8* a2f, const float* b2r, const float* b3v,
    int p, float* out)
{
    f32x16 acc1;
    #pragma unroll
    for (int q = 0; q < 16; q++) acc1[q] = 0.f;
    #pragma unroll
    for (int kq = 0; kq < 4; kq++) {
        int k0 = kq*16 + p*8;
        float4 ua = *(const float4*)&ur[k0];
        float4 ub = *(const float4*)&ur[k0 + 4];
        float4 va = *(const float4*)&vr[k0];
        float4 vb = *(const float4*)&vr[k0 + 4];
        bf16x8 bf;
        bf[0]=(__bf16)fmaxf(ua.x+va.x,0.f); bf[1]=(__bf16)fmaxf(ua.y+va.y,0.f);
        bf[2]=(__bf16)fmaxf(ua.z+va.z,0.f); bf[3]=(__bf16)fmaxf(ua.w+va.w,0.f);
        bf[4]=(__bf16)fmaxf(ub.x+vb.x,0.f); bf[5]=(__bf16)fmaxf(ub.y+vb.y,0.f);
        bf[6]=(__bf16)fmaxf(ub.z+vb.z,0.f); bf[7]=(__bf16)fmaxf(ub.w+vb.w,0.f);
        acc1 = __builtin_amdgcn_mfma_f32_32x32x16_bf16(af[kq], bf, acc1, 0, 0, 0);
    }
    bf16x8 hb0, hb1;
    #pragma unroll
    for (int q = 0; q < 8; q++) hb0[q] = (__bf16)fmaxf(acc1[q]     + b2r[q],     0.f);
    #pragma unroll
    for (int q = 0; q < 8; q++) hb1[q] = (__bf16)fmaxf(acc1[8 + q] + b2r[8 + q], 0.f);
    f32x16 acc2;
    #pragma unroll
    for (int q = 0; q < 16; q++) acc2[q] = 0.f;
    acc2 = __builtin_amdgcn_mfma_f32_32x32x16_bf16(a2f[0], hb0, acc2, 0, 0, 0);
    acc2 = __builtin_amdgcn_mfma_f32_32x32x16_bf16(a2f[1], hb1, acc2, 0, 0, 0);
    #pragma unroll
    for (int q = 0; q < 4; q++) out[q] = fmaxf(acc2[q] + b3v[q], 0.f);   // d = q + 4p (p1 q>0 -> 0)
}

template<int MODE>
__device__ __forceinline__ void edge_impl(
    const float* __restrict__ Usrc, const float* __restrict__ Vsrc,
    const float* __restrict__ w2p, const float* __restrict__ b2p,
    const float* __restrict__ w3p, const float* __restrict__ b3p,
    float* __restrict__ outp, float* uTab, float* vTab, int b)
{
    constexpr int VROWS = MODE ? NV : NN;
    int t = threadIdx.x;
    for (int i4 = t; i4 < NN*(HID/4); i4 += 256) {
        int n = i4 >> 4, c4 = i4 & 15;
        *(float4*)&uTab[n*US + c4*4] = ((const float4*)Usrc)[b*(NN*HID/4) + i4];
    }
    for (int i4 = t; i4 < VROWS*(HID/4); i4 += 256) {
        int n = i4 >> 4, c4 = i4 & 15;
        *(float4*)&vTab[n*US + c4*4] = ((const float4*)Vsrc)[b*(VROWS*HID/4) + i4];
    }

    int l = t & 63, w = t >> 6;
    int p = l >> 5, el = l & 31;

    // A1 = W2 rows el, k = kq*16 + p*8 + reg
    bf16x8 af[4];
    #pragma unroll
    for (int kq = 0; kq < 4; kq++) {
        const float* src = &w2p[el*HID + kq*16 + p*8];
        float4 a = *(const float4*)src;
        float4 c = *(const float4*)(src + 4);
        bf16x8 f;
        f[0]=(__bf16)a.x; f[1]=(__bf16)a.y; f[2]=(__bf16)a.z; f[3]=(__bf16)a.w;
        f[4]=(__bf16)c.x; f[5]=(__bf16)c.y; f[6]=(__bf16)c.z; f[7]=(__bf16)c.w;
        af[kq] = f;
    }
    // A2#m rows el (<DE else 0): slot reg i holds W3[el][(i&3)+8*(i>>2)+4p+16m]
    bf16x8 a2f[2];
    #pragma unroll
    for (int m = 0; m < 2; m++) {
        bf16x8 f;
        #pragma unroll
        for (int q = 0; q < 8; q++) f[q] = (__bf16)0.f;
        if (el < DE) {
            const float* src = &w3p[el*HH + 4*p + 16*m];
            float4 a = *(const float4*)src;        // j = 4p+16m+{0..3}
            float4 c = *(const float4*)(src + 8);  // j = 8+4p+16m+{0..3}
            f[0]=(__bf16)a.x; f[1]=(__bf16)a.y; f[2]=(__bf16)a.z; f[3]=(__bf16)a.w;
            f[4]=(__bf16)c.x; f[5]=(__bf16)c.y; f[6]=(__bf16)c.z; f[7]=(__bf16)c.w;
        }
        a2f[m] = f;
    }
    float b2r[16];
    #pragma unroll
    for (int q = 0; q < 16; q++) b2r[q] = b2p[(q&3) + 8*(q>>2) + 4*p];
    float b3v[4];
    #pragma unroll
    for (int q = 0; q < 4; q++) b3v[q] = p ? (q == 0 ? b3p[4] : 0.f) : b3p[q];

    __syncthreads();

    if (MODE == 0) {
        // wave owns r in [w*15, w*15+15); 2 tiles of 32 per r; register accumulate
        int r0 = w * 15;
        for (int rr = 0; rr < 15; rr++) {
            int r = r0 + rr;
            const float* ur = &uTab[r*US];
            float racc[4] = {0.f, 0.f, 0.f, 0.f};
            #pragma unroll
            for (int half = 0; half < 2; half++) {
                int j0 = half*32 + el;
                int s = j0 + (j0 >= r ? 1 : 0);
                s = s > 59 ? 59 : s;
                bool valid = j0 < 59;
                float val[4];
                edge_tile_compute(ur, &vTab[s*US], af, a2f, b2r, b3v, p, val);
                #pragma unroll
                for (int q = 0; q < 4; q++) racc[q] += valid ? val[q] : 0.f;
            }
            #pragma unroll
            for (int q = 0; q < 4; q++) {
                float v = racc[q];
                v += __shfl_xor(v, 1);
                v += __shfl_xor(v, 2);
                v += __shfl_xor(v, 4);
                v += __shfl_xor(v, 8);
                v += __shfl_xor(v, 16);
                racc[q] = v;
            }
            if (el == 0) {
                if (p == 0) {
                    #pragma unroll
                    for (int q = 0; q < 4; q++) outp[b*NN*DE + r*DE + q] = racc[q];
                } else {
                    outp[b*NN*DE + r*DE + 4] = racc[0];
                }
            }
        }
    } else {
        // 15 tiles of (4 r x 8 v-slots); reduce within octets; direct stores
        for (int tt = w; tt < 15; tt += 4) {
            int r = tt*4 + (el >> 3);
            int v = el & 7;
            bool valid = v < NV;
            const float* ur = &uTab[r*US];
            const float* vr = &vTab[(valid ? v : 0)*US];
            float val[4];
            edge_tile_compute(ur, vr, af, a2f, b2r, b3v, p, val);
            #pragma unroll
            for (int q = 0; q < 4; q++) {
                float x = valid ? val[q] : 0.f;
                x += __shfl_xor(x, 1);
                x += __shfl_xor(x, 2);
                x += __shfl_xor(x, 4);
                val[q] = x;
            }
            if ((el & 7) == 0) {
                if (p == 0) {
                    #pragma unroll
                    for (int q = 0; q < 4; q++) outp[b*NN*DE + r*DE + q] = val[q];
                } else {
                    outp[b*NN*DE + r*DE + 4] = val[0];
                }
            }
        }
    }
}

__global__ __launch_bounds__(256) void k_edge(
    const float* __restrict__ U, const float* __restrict__ V,
    const float* __restrict__ Uk, const float* __restrict__ Vy,
    const float* __restrict__ w2,  const float* __restrict__ b2,
    const float* __restrict__ w3,  const float* __restrict__ b3,
    const float* __restrict__ w2s, const float* __restrict__ b2s,
    const float* __restrict__ w3s, const float* __restrict__ b3s,
    float* __restrict__ Eb, float* __restrict__ Ebs)
{
    __shared__ float uTab[NN*US];
    __shared__ float vTab[NN*US];
    if (blockIdx.x < BB)
        edge_impl<0>(U, V, w2, b2, w3, b3, Eb, uTab, vTab, blockIdx.x);
    else
        edge_impl<1>(Uk, Vy, w2s, b2s, w3s, b3s, Ebs, uTab, vTab, blockIdx.x - BB);
}

// ---------------- K4: node MLP + node-sum + final head ----------------
#define CS 40
#define CSP 41
#define HSP 68
__global__ __launch_bounds__(256) void k4_out(
    const float* __restrict__ x, const float* __restrict__ Eb, const float* __restrict__ Ebs,
    const float* __restrict__ w1g, const float* __restrict__ b1g,
    const float* __restrict__ w2g, const float* __restrict__ b2g,
    const float* __restrict__ w3g, const float* __restrict__ b3g,
    const float* __restrict__ fcw, const float* __restrict__ fcb,
    float* __restrict__ out)
{
    __shared__ float cl[NN*CSP];
    __shared__ float hl[NN*HSP];
    __shared__ float pl[NN*4*DO_];
    __shared__ float nsum[DO_];
    int b = blockIdx.x, t = threadIdx.x;
    // coalesced staging
    for (int i = t; i < PP*NN; i += 256) { int c = i/NN, n = i - c*NN; cl[n*CSP + c] = x[b*PP*NN + i]; }
    for (int i = t; i < NN*DE; i += 256) {
        int n = i/DE, d = i - n*DE;
        cl[n*CSP + PP + d]      = Eb [b*NN*DE + i];
        cl[n*CSP + PP + DE + d] = Ebs[b*NN*DE + i];
    }
    if (t < DO_) nsum[t] = 0.f;
    __syncthreads();

    int n = t & 63;
    int rep = __builtin_amdgcn_readfirstlane(t >> 6);
    if (n < NN) {
        float c_[CS];
        #pragma unroll
        for (int c = 0; c < CS; c++) c_[c] = cl[n*CSP + c];
        #pragma unroll
        for (int kk = 0; kk < 16; kk++) {
            int k = rep*16 + kk;                        // uniform -> s_load weights
            float s = b1g[k];
            #pragma unroll
            for (int c = 0; c < CS; c++) s += w1g[k*CS + c] * c_[c];
            hl[n*HSP + k] = fmaxf(s, 0.f);
        }
    }
    __syncthreads();
    if (n < NN) {
        float acc[8];
        #pragma unroll
        for (int jj = 0; jj < 8; jj++) acc[jj] = b2g[rep*8 + jj];
        for (int kq = 0; kq < HID/4; kq++) {
            float4 h4 = *(const float4*)&hl[n*HSP + kq*4];
            #pragma unroll
            for (int jj = 0; jj < 8; jj++) {
                const float4 wv = *(const float4*)&w2g[(rep*8 + jj)*HID + kq*4];
                acc[jj] += wv.x*h4.x + wv.y*h4.y + wv.z*h4.z + wv.w*h4.w;
            }
        }
        #pragma unroll
        for (int d = 0; d < DO_; d++) {
            float s = 0.f;
            #pragma unroll
            for (int jj = 0; jj < 8; jj++) s += w3g[d*HH + rep*8 + jj] * fmaxf(acc[jj], 0.f);
            pl[(n*4 + rep)*DO_ + d] = s;
        }
    }
    __syncthreads();
    if (t < NN) {
        #pragma unroll
        for (int d = 0; d < DO_; d++) {
            float s = b3g[d] + pl[(t*4+0)*DO_+d] + pl[(t*4+1)*DO_+d]
                             + pl[(t*4+2)*DO_+d] + pl[(t*4+3)*DO_+d];
            atomicAdd(&nsum[d], fmaxf(s, 0.f));
        }
    }
    __syncthreads();
    if (t < NT) {
        float s = fcb[t];
        #pragma unroll
        for (int d = 0; d < DO_; d++) s += fcw[t*DO_ + d] * nsum[d];
        out[b*NT + t] = fmaxf(s, 0.f);
    }
}

extern "C" void kernel_launch(void* const* d_in, const int* in_sizes, int n_in,
                              void* d_out, int out_size, void* d_ws, size_t ws_size,
                              hipStream_t stream)
{
    const float* x      = (const float*)d_in[0];
    const float* y      = (const float*)d_in[1];
    const float* fr1_w  = (const float*)d_in[2];  const float* fr1_b  = (const float*)d_in[3];
    const float* fr2_w  = (const float*)d_in[4];  const float* fr2_b  = (const float*)d_in[5];
    const float* fr3_w  = (const float*)d_in[6];  const float* fr3_b  = (const float*)d_in[7];
    const float* fr1s_w = (const float*)d_in[8];  const float* fr1s_b = (const float*)d_in[9];
    const float* fr2s_w = (const float*)d_in[10]; const float* fr2s_b = (const float*)d_in[11];
    const float* fr3s_w = (const float*)d_in[12]; const float* fr3s_b = (const float*)d_in[13];
    const float* fo1_w  = (const float*)d_in[14]; const float* fo1_b  = (const float*)d_in[15];
    const float* fo2_w  = (const float*)d_in[16]; const float* fo2_b  = (const float*)d_in[17];
    const float* fo3_w  = (const float*)d_in[18]; const float* fo3_b  = (const float*)d_in[19];
    const float* fcf_w  = (const float*)d_in[20]; const float* fcf_b  = (const float*)d_in[21];

    float* ws  = (float*)d_ws;
    float* U   = ws + OFF_U;
    float* V   = ws + OFF_V;
    float* Uk  = ws + OFF_UK;
    float* Vy  = ws + OFF_VY;
    float* Eb  = ws + OFF_EB;
    float* Ebs = ws + OFF_EBS;

    hipLaunchKernelGGL(k1_proj, dim3(BB), dim3(256), 0, stream,
                       x, y, fr1_w, fr1_b, fr1s_w, fr1s_b, U, V, Uk, Vy);
    hipLaunchKernelGGL(k_edge, dim3(2*BB), dim3(256), 0, stream,
                       U, V, Uk, Vy, fr2_w, fr2_b, fr3_w, fr3_b,
                       fr2s_w, fr2s_b, fr3s_w, fr3s_b, Eb, Ebs);
    hipLaunchKernelGGL(k4_out, dim3(BB), dim3(256), 0, stream,
                       x, Eb, Ebs, fo1_w, fo1_b, fo2_w, fo2_b, fo3_w, fo3_b, fcf_w, fcf_b,
                       (float*)d_out);
}

// Round 10
// 164.698 us; speedup vs baseline: 3.1908x; 1.0985x over previous
//
#include <hip/hip_runtime.h>

#define BB 512
#define PP 30
#define NN 60
#define SS 14
#define NV 5
#define HID 64
#define HH 32
#define DE 5
#define DO_ 6
#define NT 2
#define CS 40
#define CSP 41
#define HSP 68

typedef __bf16 bf16x8 __attribute__((ext_vector_type(8)));
typedef float  f32x16 __attribute__((ext_vector_type(16)));

union B8u { bf16x8 v; uint4 u; };

__device__ __forceinline__ void unpk2(unsigned int wv, float* f) {
    f[0] = __uint_as_float(wv << 16);
    f[1] = __uint_as_float(wv & 0xffff0000u);
}

// A1 frags: W2 rows el, k = kq*16 + p*8 + q.  A2 frags: W3 rows el (<DE else 0),
// slot q holds W3[el][(q&3)+8*(q>>2)+4p+16m] (matches D1 reg->j map). Round-7-verified.
__device__ __forceinline__ void load_frags(
    const float* __restrict__ w2p, const float* __restrict__ b2p,
    const float* __restrict__ w3p, const float* __restrict__ b3p,
    int el, int p, bf16x8* af, bf16x8* a2f, float* b2r, float* b3v)
{
    #pragma unroll
    for (int kq = 0; kq < 4; kq++) {
        const float* src = &w2p[el*HID + kq*16 + p*8];
        float4 a = *(const float4*)src;
        float4 c = *(const float4*)(src + 4);
        bf16x8 f;
        f[0]=(__bf16)a.x; f[1]=(__bf16)a.y; f[2]=(__bf16)a.z; f[3]=(__bf16)a.w;
        f[4]=(__bf16)c.x; f[5]=(__bf16)c.y; f[6]=(__bf16)c.z; f[7]=(__bf16)c.w;
        af[kq] = f;
    }
    #pragma unroll
    for (int m = 0; m < 2; m++) {
        bf16x8 f;
        #pragma unroll
        for (int q = 0; q < 8; q++) f[q] = (__bf16)0.f;
        if (el < DE) {
            const float* src = &w3p[el*HH + 4*p + 16*m];
            float4 a = *(const float4*)src;
            float4 c = *(const float4*)(src + 8);
            f[0]=(__bf16)a.x; f[1]=(__bf16)a.y; f[2]=(__bf16)a.z; f[3]=(__bf16)a.w;
            f[4]=(__bf16)c.x; f[5]=(__bf16)c.y; f[6]=(__bf16)c.z; f[7]=(__bf16)c.w;
        }
        a2f[m] = f;
    }
    #pragma unroll
    for (int q = 0; q < 16; q++) b2r[q] = b2p[(q&3) + 8*(q>>2) + 4*p];
    #pragma unroll
    for (int q = 0; q < 4; q++) b3v[q] = p ? (q == 0 ? b3p[4] : 0.f) : b3p[q];
}

// lane's u-slice (32 f32) for row r from a swizzled bf16 table
__device__ __forceinline__ void load_u(const __bf16* tab, int r, int p, float* uf) {
    #pragma unroll
    for (int kq = 0; kq < 4; kq++) {
        int off = (kq*16 + p*8) ^ ((r & 7) << 3);
        B8u ub; ub.v = *(const bf16x8*)&tab[r*64 + off];
        unpk2(ub.u.x, uf + kq*8);     unpk2(ub.u.y, uf + kq*8 + 2);
        unpk2(ub.u.z, uf + kq*8 + 4); unpk2(ub.u.w, uf + kq*8 + 6);
    }
}

// 32-edge tile: layer2 (4 MFMA 32x32x16) + layer3 (2 MFMA). Round-7-verified math.
__device__ __forceinline__ void tile_compute(
    const float* uf, const __bf16* vtab, int vn,
    const bf16x8* af, const bf16x8* a2f, const float* b2r, const float* b3v,
    int p, float* out)
{
    f32x16 acc1;
    #pragma unroll
    for (int q = 0; q < 16; q++) acc1[q] = 0.f;
    #pragma unroll
    for (int kq = 0; kq < 4; kq++) {
        int off = (kq*16 + p*8) ^ ((vn & 7) << 3);
        B8u vb; vb.v = *(const bf16x8*)&vtab[vn*64 + off];
        float vf[8];
        unpk2(vb.u.x, vf); unpk2(vb.u.y, vf+2); unpk2(vb.u.z, vf+4); unpk2(vb.u.w, vf+6);
        bf16x8 bf;
        #pragma unroll
        for (int i = 0; i < 8; i++) bf[i] = (__bf16)fmaxf(uf[kq*8 + i] + vf[i], 0.f);
        acc1 = __builtin_amdgcn_mfma_f32_32x32x16_bf16(af[kq], bf, acc1, 0, 0, 0);
    }
    bf16x8 hb0, hb1;
    #pragma unroll
    for (int q = 0; q < 8; q++) hb0[q] = (__bf16)fmaxf(acc1[q]     + b2r[q],     0.f);
    #pragma unroll
    for (int q = 0; q < 8; q++) hb1[q] = (__bf16)fmaxf(acc1[8 + q] + b2r[8 + q], 0.f);
    f32x16 acc2;
    #pragma unroll
    for (int q = 0; q < 16; q++) acc2[q] = 0.f;
    acc2 = __builtin_amdgcn_mfma_f32_32x32x16_bf16(a2f[0], hb0, acc2, 0, 0, 0);
    acc2 = __builtin_amdgcn_mfma_f32_32x32x16_bf16(a2f[1], hb1, acc2, 0, 0, 0);
    #pragma unroll
    for (int q = 0; q < 4; q++) out[q] = fmaxf(acc2[q] + b3v[q], 0.f);
}

__global__ __launch_bounds__(256) void k_fused(
    const float* __restrict__ x, const float* __restrict__ y,
    const float* __restrict__ fr1_w, const float* __restrict__ fr1_b,
    const float* __restrict__ fr2_w, const float* __restrict__ fr2_b,
    const float* __restrict__ fr3_w, const float* __restrict__ fr3_b,
    const float* __restrict__ fr1s_w, const float* __restrict__ fr1s_b,
    const float* __restrict__ fr2s_w, const float* __restrict__ fr2s_b,
    const float* __restrict__ fr3s_w, const float* __restrict__ fr3s_b,
    const float* __restrict__ fo1_w, const float* __restrict__ fo1_b,
    const float* __restrict__ fo2_w, const float* __restrict__ fo2_b,
    const float* __restrict__ fo3_w, const float* __restrict__ fo3_b,
    const float* __restrict__ fcw, const float* __restrict__ fcb,
    float* __restrict__ out)
{
    __shared__ alignas(16) __bf16 uT[NN*64];     // swizzled bf16 node tables
    __shared__ alignas(16) __bf16 vT[NN*64];
    __shared__ alignas(16) __bf16 ukT[NN*64];
    __shared__ alignas(16) __bf16 vyT[8*64];
    __shared__ float cl[NN*CSP];
    __shared__ float hl[NN*HSP];
    __shared__ float pl[NN*4*DO_];
    __shared__ float nsum[DO_];

    int b = blockIdx.x, t = threadIdx.x;
    int h = t & 63;
    int w = __builtin_amdgcn_readfirstlane(t >> 6);

    if (t < DO_) nsum[t] = 0.f;
    // stage x columns into cl (c<PP), coalesced
    for (int i = t; i < PP*NN; i += 256) {
        int c = i / NN, n = i - c*NN;
        cl[n*CSP + c] = x[b*PP*NN + i];
    }

    // ---- Phase A: projections U, V(+b1), Uk, Vy(+b1s) -> swizzled bf16 LDS ----
    {
        float wu[PP], wv[PP], wk[PP];
        #pragma unroll
        for (int p2 = 0; p2 < PP; p2++) {
            wu[p2] = fr1_w[h*2*PP + p2];
            wv[p2] = fr1_w[h*2*PP + PP + p2];
            wk[p2] = fr1s_w[h*(SS+PP) + p2];
        }
        float b1h = fr1_b[h];
        const float* xb = x + b*PP*NN;
        for (int rr = 0; rr < 15; rr++) {
            int n = w*15 + rr;
            float su = 0.f, sv = 0.f, sk = 0.f;
            #pragma unroll
            for (int p2 = 0; p2 < PP; p2++) {
                float xv = xb[p2*NN + n];       // wave-uniform address -> s_load
                su += wu[p2]*xv; sv += wv[p2]*xv; sk += wk[p2]*xv;
            }
            int idx = n*64 + (h ^ ((n & 7) << 3));
            uT[idx]  = (__bf16)su;
            vT[idx]  = (__bf16)(sv + b1h);
            ukT[idx] = (__bf16)sk;
        }
        if (w == 0) {
            float wy[SS];
            #pragma unroll
            for (int q = 0; q < SS; q++) wy[q] = fr1s_w[h*(SS+PP) + PP + q];
            float b1s = fr1s_b[h];
            #pragma unroll
            for (int v = 0; v < NV; v++) {
                float s = 0.f;
                #pragma unroll
                for (int q = 0; q < SS; q++) s += wy[q] * y[b*SS*NV + q*NV + v];
                vyT[v*64 + (h ^ (v << 3))] = (__bf16)(s + b1s);
            }
        }
    }
    __syncthreads();

    // ---- Phase B: edge MLPs (MFMA), results straight into cl ----
    int p = h >> 5, el = h & 31;
    {   // node-node edges
        bf16x8 af[4], a2f[2]; float b2r[16], b3v[4];
        load_frags(fr2_w, fr2_b, fr3_w, fr3_b, el, p, af, a2f, b2r, b3v);
        for (int rr = 0; rr < 15; rr++) {
            int r = w*15 + rr;
            float uf[32];
            load_u(uT, r, p, uf);
            float racc[4] = {0.f, 0.f, 0.f, 0.f};
            #pragma unroll
            for (int half = 0; half < 2; half++) {
                int j0 = half*32 + el;
                int s = j0 + (j0 >= r ? 1 : 0);
                s = s > 59 ? 59 : s;
                bool valid = j0 < 59;
                float val[4];
                tile_compute(uf, vT, s, af, a2f, b2r, b3v, p, val);
                #pragma unroll
                for (int q = 0; q < 4; q++) racc[q] += valid ? val[q] : 0.f;
            }
            #pragma unroll
            for (int q = 0; q < 4; q++) {
                float v2 = racc[q];
                v2 += __shfl_xor(v2, 1);
                v2 += __shfl_xor(v2, 2);
                v2 += __shfl_xor(v2, 4);
                v2 += __shfl_xor(v2, 8);
                v2 += __shfl_xor(v2, 16);
                racc[q] = v2;
            }
            if (el == 0) {
                if (p == 0) {
                    #pragma unroll
                    for (int q = 0; q < 4; q++) cl[r*CSP + PP + q] = racc[q];
                } else {
                    cl[r*CSP + PP + 4] = racc[0];
                }
            }
        }
    }
    {   // node-view edges
        bf16x8 af[4], a2f[2]; float b2r[16], b3v[4];
        load_frags(fr2s_w, fr2s_b, fr3s_w, fr3s_b, el, p, af, a2f, b2r, b3v);
        for (int tt = w; tt < 15; tt += 4) {
            int r = tt*4 + (el >> 3);
            int v = el & 7;
            bool valid = v < NV;
            float uf[32];
            load_u(ukT, r, p, uf);
            float val[4];
            tile_compute(uf, vyT, valid ? v : 0, af, a2f, b2r, b3v, p, val);
            #pragma unroll
            for (int q = 0; q < 4; q++) {
                float x2 = valid ? val[q] : 0.f;
                x2 += __shfl_xor(x2, 1);
                x2 += __shfl_xor(x2, 2);
                x2 += __shfl_xor(x2, 4);
                val[q] = x2;
            }
            if ((el & 7) == 0) {
                if (p == 0) {
                    #pragma unroll
                    for (int q = 0; q < 4; q++) cl[r*CSP + PP + DE + q] = val[q];
                } else {
                    cl[r*CSP + PP + DE + 4] = val[0];
                }
            }
        }
    }
    __syncthreads();

    // ---- Phase D: node MLP + node-sum + final head ----
    {
        int n = h, rep = w;
        if (n < NN) {
            float c_[CS];
            #pragma unroll
            for (int c = 0; c < CS; c++) c_[c] = cl[n*CSP + c];
            #pragma unroll
            for (int kk = 0; kk < 16; kk++) {
                int k = rep*16 + kk;                 // uniform -> s_load weights
                float s = fo1_b[k];
                #pragma unroll
                for (int c = 0; c < CS; c++) s += fo1_w[k*CS + c] * c_[c];
                hl[n*HSP + k] = fmaxf(s, 0.f);
            }
        }
        __syncthreads();
        if (n < NN) {
            float acc[8];
            #pragma unroll
            for (int jj = 0; jj < 8; jj++) acc[jj] = fo2_b[rep*8 + jj];
            for (int kq = 0; kq < HID/4; kq++) {
                float4 h4 = *(const float4*)&hl[n*HSP + kq*4];
                #pragma unroll
                for (int jj = 0; jj < 8; jj++) {
                    const float4 wv4 = *(const float4*)&fo2_w[(rep*8 + jj)*HID + kq*4];
                    acc[jj] += wv4.x*h4.x + wv4.y*h4.y + wv4.z*h4.z + wv4.w*h4.w;
                }
            }
            #pragma unroll
            for (int d = 0; d < DO_; d++) {
                float s = 0.f;
                #pragma unroll
                for (int jj = 0; jj < 8; jj++) s += fo3_w[d*HH + rep*8 + jj] * fmaxf(acc[jj], 0.f);
                pl[(n*4 + rep)*DO_ + d] = s;
            }
        }
        __syncthreads();
        if (t < NN) {
            #pragma unroll
            for (int d = 0; d < DO_; d++) {
                float s = fo3_b[d] + pl[(t*4+0)*DO_+d] + pl[(t*4+1)*DO_+d]
                                   + pl[(t*4+2)*DO_+d] + pl[(t*4+3)*DO_+d];
                atomicAdd(&nsum[d], fmaxf(s, 0.f));
            }
        }
        __syncthreads();
        if (t < NT) {
            float s = fcb[t];
            #pragma unroll
            for (int d = 0; d < DO_; d++) s += fcw[t*DO_ + d] * nsum[d];
            out[b*NT + t] = fmaxf(s, 0.f);
        }
    }
}

extern "C" void kernel_launch(void* const* d_in, const int* in_sizes, int n_in,
                              void* d_out, int out_size, void* d_ws, size_t ws_size,
                              hipStream_t stream)
{
    const float* x      = (const float*)d_in[0];
    const float* y      = (const float*)d_in[1];
    const float* fr1_w  = (const float*)d_in[2];  const float* fr1_b  = (const float*)d_in[3];
    const float* fr2_w  = (const float*)d_in[4];  const float* fr2_b  = (const float*)d_in[5];
    const float* fr3_w  = (const float*)d_in[6];  const float* fr3_b  = (const float*)d_in[7];
    const float* fr1s_w = (const float*)d_in[8];  const float* fr1s_b = (const float*)d_in[9];
    const float* fr2s_w = (const float*)d_in[10]; const float* fr2s_b = (const float*)d_in[11];
    const float* fr3s_w = (const float*)d_in[12]; const float* fr3s_b = (const float*)d_in[13];
    const float* fo1_w  = (const float*)d_in[14]; const float* fo1_b  = (const float*)d_in[15];
    const float* fo2_w  = (const float*)d_in[16]; const float* fo2_b  = (const float*)d_in[17];
    const float* fo3_w  = (const float*)d_in[18]; const float* fo3_b  = (const float*)d_in[19];
    const float* fcf_w  = (const float*)d_in[20]; const float* fcf_b  = (const float*)d_in[21];

    hipLaunchKernelGGL(k_fused, dim3(BB), dim3(256), 0, stream,
                       x, y, fr1_w, fr1_b, fr2_w, fr2_b, fr3_w, fr3_b,
                       fr1s_w, fr1s_b, fr2s_w, fr2s_b, fr3s_w, fr3s_b,
                       fo1_w, fo1_b, fo2_w, fo2_b, fo3_w, fo3_b, fcf_w, fcf_b,
                       (float*)d_out);
}

// Round 13
// 142.660 us; speedup vs baseline: 3.6837x; 1.1545x over previous
//
#include <hip/hip_runtime.h>
#include <hip/hip_fp16.h>

#define BB 512
#define PP 30
#define NN 60
#define SS 14
#define NV 5
#define HID 64
#define HH 32
#define DE 5
#define DO_ 6
#define NT 2
#define CS 40
#define CSP 41
#define NW 8    // waves per block (512 threads)

typedef _Float16 f16;
typedef f16 f16x8 __attribute__((ext_vector_type(8)));
typedef __fp16 fp16x2 __attribute__((ext_vector_type(2)));
typedef float f32x16 __attribute__((ext_vector_type(16)));

union H8 { f16x8 v; unsigned u32[4]; uint4 u; };
union CV { fp16x2 h; unsigned u; };

// packed fp16: r = max(a + b, 0) on 2 lanes (v_pk_add_f16 + v_pk_max_f16)
__device__ __forceinline__ unsigned pk_addrelu(unsigned a, unsigned b) {
    unsigned s, r;
    asm("v_pk_add_f16 %0, %1, %2" : "=v"(s) : "v"(a), "v"(b));
    asm("v_pk_max_f16 %0, %1, 0"  : "=v"(r) : "v"(s));
    return r;
}

// A1 frags: W2 rows el, k = kq*16 + p*8 + q.  A2#m rows el (<DE else 0): slot q holds
// W3[el][(q&3)+8*(q>>2)+4p+16m], matching D1's reg->j map (HW-verified rounds 6-7, bf16->fp16 dtype swap).
__device__ __forceinline__ void load_frags(
    const float* __restrict__ w2p, const float* __restrict__ b2p,
    const float* __restrict__ w3p, const float* __restrict__ b3p,
    int el, int p, f16x8* af, f16x8* a2f, float* b2r, float* b3v)
{
    #pragma unroll
    for (int kq = 0; kq < 4; kq++) {
        const float* src = &w2p[el*HID + kq*16 + p*8];
        float4 a = *(const float4*)src;
        float4 c = *(const float4*)(src + 4);
        f16x8 f;
        f[0]=(f16)a.x; f[1]=(f16)a.y; f[2]=(f16)a.z; f[3]=(f16)a.w;
        f[4]=(f16)c.x; f[5]=(f16)c.y; f[6]=(f16)c.z; f[7]=(f16)c.w;
        af[kq] = f;
    }
    #pragma unroll
    for (int m = 0; m < 2; m++) {
        f16x8 f;
        #pragma unroll
        for (int q = 0; q < 8; q++) f[q] = (f16)0.f;
        if (el < DE) {
            const float* src = &w3p[el*HH + 4*p + 16*m];
            float4 a = *(const float4*)src;
            float4 c = *(const float4*)(src + 8);
            f[0]=(f16)a.x; f[1]=(f16)a.y; f[2]=(f16)a.z; f[3]=(f16)a.w;
            f[4]=(f16)c.x; f[5]=(f16)c.y; f[6]=(f16)c.z; f[7]=(f16)c.w;
        }
        a2f[m] = f;
    }
    #pragma unroll
    for (int q = 0; q < 16; q++) b2r[q] = b2p[(q&3) + 8*(q>>2) + 4*p];
    #pragma unroll
    for (int q = 0; q < 4; q++) b3v[q] = p ? (q == 0 ? b3p[4] : 0.f) : b3p[q];
}

// lane's packed u-slice (32 fp16 in 4x uint4) for row r from swizzled table
__device__ __forceinline__ void load_u(const __half* tab, int r, int p, H8* u8) {
    #pragma unroll
    for (int kq = 0; kq < 4; kq++) {
        int off = (kq*16 + p*8) ^ ((r & 7) << 3);
        u8[kq].u = *(const uint4*)&tab[r*64 + off];
    }
}

// 32-edge tile: layer2 (4 MFMA 32x32x16 f16) + layer3 (2 MFMA). Packed fp16 h1 build.
__device__ __forceinline__ void tile_compute(
    const H8* u8, const __half* vtab, int vn,
    const f16x8* af, const f16x8* a2f, const float* b2r, const float* b3v,
    int p, float* out)
{
    f32x16 acc1;
    #pragma unroll
    for (int q = 0; q < 16; q++) acc1[q] = 0.f;
    #pragma unroll
    for (int kq = 0; kq < 4; kq++) {
        int off = (kq*16 + p*8) ^ ((vn & 7) << 3);
        H8 vb; vb.u = *(const uint4*)&vtab[vn*64 + off];
        H8 hb;
        #pragma unroll
        for (int j = 0; j < 4; j++) hb.u32[j] = pk_addrelu(u8[kq].u32[j], vb.u32[j]);
        acc1 = __builtin_amdgcn_mfma_f32_32x32x16_f16(af[kq], hb.v, acc1, 0, 0, 0);
    }
    H8 hb0, hb1;
    #pragma unroll
    for (int i = 0; i < 4; i++) {
        CV c0, c1;
        c0.h = __builtin_amdgcn_cvt_pkrtz(fmaxf(acc1[2*i]   + b2r[2*i],   0.f),
                                          fmaxf(acc1[2*i+1] + b2r[2*i+1], 0.f));
        c1.h = __builtin_amdgcn_cvt_pkrtz(fmaxf(acc1[8+2*i]   + b2r[8+2*i],   0.f),
                                          fmaxf(acc1[8+2*i+1] + b2r[8+2*i+1], 0.f));
        hb0.u32[i] = c0.u;
        hb1.u32[i] = c1.u;
    }
    f32x16 acc2;
    #pragma unroll
    for (int q = 0; q < 16; q++) acc2[q] = 0.f;
    acc2 = __builtin_amdgcn_mfma_f32_32x32x16_f16(a2f[0], hb0.v, acc2, 0, 0, 0);
    acc2 = __builtin_amdgcn_mfma_f32_32x32x16_f16(a2f[1], hb1.v, acc2, 0, 0, 0);
    #pragma unroll
    for (int q = 0; q < 4; q++) out[q] = fmaxf(acc2[q] + b3v[q], 0.f);
}

__global__ __launch_bounds__(512, 4) void k_fused(
    const float* __restrict__ x, const float* __restrict__ y,
    const float* __restrict__ fr1_w, const float* __restrict__ fr1_b,
    const float* __restrict__ fr2_w, const float* __restrict__ fr2_b,
    const float* __restrict__ fr3_w, const float* __restrict__ fr3_b,
    const float* __restrict__ fr1s_w, const float* __restrict__ fr1s_b,
    const float* __restrict__ fr2s_w, const float* __restrict__ fr2s_b,
    const float* __restrict__ fr3s_w, const float* __restrict__ fr3s_b,
    const float* __restrict__ fo1_w, const float* __restrict__ fo1_b,
    const float* __restrict__ fo2_w, const float* __restrict__ fo2_b,
    const float* __restrict__ fo3_w, const float* __restrict__ fo3_b,
    const float* __restrict__ fcw, const float* __restrict__ fcb,
    float* __restrict__ out)
{
    // phase A/B: 3 fp16 tables (23040 B) ; phase D: hl[64][60] + pl[48][60] (26880 B) — aliased
    __shared__ alignas(16) char smem[26880];
    __half* uT  = (__half*)smem;              // [NN][64] swizzled fp16
    __half* vT  = (__half*)(smem + 7680);
    __half* ukT = (__half*)(smem + 15360);
    float*  hl  = (float*)smem;               // [HID][NN]
    float*  pl  = (float*)(smem + 15360);     // [48][NN]
    __shared__ alignas(16) __half vyT[8*64];
    __shared__ float cl[NN*CSP];
    __shared__ float nsum[DO_];

    int b = blockIdx.x, t = threadIdx.x;
    int h = t & 63;
    int w = __builtin_amdgcn_readfirstlane(t >> 6);

    if (t < DO_) nsum[t] = 0.f;
    // stage x columns into cl (c<PP), coalesced
    for (int i = t; i < PP*NN; i += 512) {
        int c = i / NN, n = i - c*NN;
        cl[n*CSP + c] = x[b*PP*NN + i];
    }

    // ---- Phase A: projections -> swizzled fp16 LDS tables ----
    {
        float wu[PP], wv[PP], wk[PP];
        #pragma unroll
        for (int p2 = 0; p2 < PP; p2++) {
            wu[p2] = fr1_w[h*2*PP + p2];
            wv[p2] = fr1_w[h*2*PP + PP + p2];
            wk[p2] = fr1s_w[h*(SS+PP) + p2];
        }
        float b1h = fr1_b[h];
        const float* xb = x + b*PP*NN;
        for (int n = w; n < NN; n += NW) {
            float su = 0.f, sv = 0.f, sk = 0.f;
            #pragma unroll
            for (int p2 = 0; p2 < PP; p2++) {
                float xv = xb[p2*NN + n];       // wave-uniform address -> s_load
                su += wu[p2]*xv; sv += wv[p2]*xv; sk += wk[p2]*xv;
            }
            int idx = n*64 + (h ^ ((n & 7) << 3));
            uT[idx]  = (__half)su;
            vT[idx]  = (__half)(sv + b1h);
            ukT[idx] = (__half)sk;
        }
        if (w == 0) {
            float wy[SS];
            #pragma unroll
            for (int q = 0; q < SS; q++) wy[q] = fr1s_w[h*(SS+PP) + PP + q];
            float b1s = fr1s_b[h];
            #pragma unroll
            for (int v = 0; v < NV; v++) {
                float s = 0.f;
                #pragma unroll
                for (int q = 0; q < SS; q++) s += wy[q] * y[b*SS*NV + q*NV + v];
                vyT[v*64 + (h ^ (v << 3))] = (__half)(s + b1s);
            }
        }
    }
    __syncthreads();

    // ---- Phase B: edge MLPs (fp16 MFMA), results into cl ----
    int p = h >> 5, el = h & 31;
    {   // node-node edges: wave owns r = w, w+8, ...
        f16x8 af[4], a2f[2]; float b2r[16], b3v[4];
        load_frags(fr2_w, fr2_b, fr3_w, fr3_b, el, p, af, a2f, b2r, b3v);
        for (int r = w; r < NN; r += NW) {
            H8 u8[4];
            load_u(uT, r, p, u8);
            float racc[4] = {0.f, 0.f, 0.f, 0.f};
            #pragma unroll
            for (int half = 0; half < 2; half++) {
                int j0 = half*32 + el;
                int s = j0 + (j0 >= r ? 1 : 0);
                s = s > 59 ? 59 : s;
                bool valid = j0 < 59;
                float val[4];
                tile_compute(u8, vT, s, af, a2f, b2r, b3v, p, val);
                #pragma unroll
                for (int q = 0; q < 4; q++) racc[q] += valid ? val[q] : 0.f;
            }
            #pragma unroll
            for (int q = 0; q < 4; q++) {
                float v2 = racc[q];
                v2 += __shfl_xor(v2, 1);
                v2 += __shfl_xor(v2, 2);
                v2 += __shfl_xor(v2, 4);
                v2 += __shfl_xor(v2, 8);
                v2 += __shfl_xor(v2, 16);
                racc[q] = v2;
            }
            if (el == 0) {
                if (p == 0) {
                    #pragma unroll
                    for (int q = 0; q < 4; q++) cl[r*CSP + PP + q] = racc[q];
                } else {
                    cl[r*CSP + PP + 4] = racc[0];
                }
            }
        }
    }
    {   // node-view edges: 15 tiles of (4 r x 8 v-slots)
        f16x8 af[4], a2f[2]; float b2r[16], b3v[4];
        load_frags(fr2s_w, fr2s_b, fr3s_w, fr3s_b, el, p, af, a2f, b2r, b3v);
        for (int tt = w; tt < 15; tt += NW) {
            int r = tt*4 + (el >> 3);
            int v = el & 7;
            bool valid = v < NV;
            H8 u8[4];
            load_u(ukT, r, p, u8);
            float val[4];
            tile_compute(u8, vyT, valid ? v : 0, af, a2f, b2r, b3v, p, val);
            #pragma unroll
            for (int q = 0; q < 4; q++) {
                float x2 = valid ? val[q] : 0.f;
                x2 += __shfl_xor(x2, 1);
                x2 += __shfl_xor(x2, 2);
                x2 += __shfl_xor(x2, 4);
                val[q] = x2;
            }
            if ((el & 7) == 0) {
                if (p == 0) {
                    #pragma unroll
                    for (int q = 0; q < 4; q++) cl[r*CSP + PP + DE + q] = val[q];
                } else {
                    cl[r*CSP + PP + DE + 4] = val[0];
                }
            }
        }
    }
    __syncthreads();

    // ---- Phase D: node MLP + node-sum + final head (hl/pl alias dead tables) ----
    {
        int n = h;  // lane = node
        if (n < NN) {
            float c_[CS];
            #pragma unroll
            for (int c = 0; c < CS; c++) c_[c] = cl[n*CSP + c];
            #pragma unroll
            for (int kk = 0; kk < 8; kk++) {
                int k = w*8 + kk;                    // uniform -> s_load weights
                float s = fo1_b[k];
                #pragma unroll
                for (int c = 0; c < CS; c++) s += fo1_w[k*CS + c] * c_[c];
                hl[k*NN + n] = fmaxf(s, 0.f);        // lane-consecutive: conflict-free
            }
        }
        __syncthreads();
        if (n < NN) {
            float acc[4];
            #pragma unroll
            for (int jj = 0; jj < 4; jj++) acc[jj] = fo2_b[w*4 + jj];
            for (int k = 0; k < HID; k++) {
                float hv = hl[k*NN + n];
                #pragma unroll
                for (int jj = 0; jj < 4; jj++) acc[jj] += fo2_w[(w*4 + jj)*HID + k] * hv;
            }
            #pragma unroll
            for (int d = 0; d < DO_; d++) {
                float s = 0.f;
                #pragma unroll
                for (int jj = 0; jj < 4; jj++) s += fo3_w[d*HH + w*4 + jj] * fmaxf(acc[jj], 0.f);
                pl[(w*DO_ + d)*NN + n] = s;
            }
        }
        __syncthreads();
        if (t < NN) {
            #pragma unroll
            for (int d = 0; d < DO_; d++) {
                float s = fo3_b[d];
                #pragma unroll
                for (int g = 0; g < NW; g++) s += pl[(g*DO_ + d)*NN + t];
                atomicAdd(&nsum[d], fmaxf(s, 0.f));
            }
        }
        __syncthreads();
        if (t < NT) {
            float s = fcb[t];
            #pragma unroll
            for (int d = 0; d < DO_; d++) s += fcw[t*DO_ + d] * nsum[d];
            out[b*NT + t] = fmaxf(s, 0.f);
        }
    }
}

extern "C" void kernel_launch(void* const* d_in, const int* in_sizes, int n_in,
                              void* d_out, int out_size, void* d_ws, size_t ws_size,
                              hipStream_t stream)
{
    const float* x      = (const float*)d_in[0];
    const float* y      = (const float*)d_in[1];
    const float* fr1_w  = (const float*)d_in[2];  const float* fr1_b  = (const float*)d_in[3];
    const float* fr2_w  = (const float*)d_in[4];  const float* fr2_b  = (const float*)d_in[5];
    const float* fr3_w  = (const float*)d_in[6];  const float* fr3_b  = (const float*)d_in[7];
    const float* fr1s_w = (const float*)d_in[8];  const float* fr1s_b = (const float*)d_in[9];
    const float* fr2s_w = (const float*)d_in[10]; const float* fr2s_b = (const float*)d_in[11];
    const float* fr3s_w = (const float*)d_in[12]; const float* fr3s_b = (const float*)d_in[13];
    const float* fo1_w  = (const float*)d_in[14]; const float* fo1_b  = (const float*)d_in[15];
    const float* fo2_w  = (const float*)d_in[16]; const float* fo2_b  = (const float*)d_in[17];
    const float* fo3_w  = (const float*)d_in[18]; const float* fo3_b  = (const float*)d_in[19];
    const float* fcf_w  = (const float*)d_in[20]; const float* fcf_b  = (const float*)d_in[21];

    hipLaunchKernelGGL(k_fused, dim3(BB), dim3(512), 0, stream,
                       x, y, fr1_w, fr1_b, fr2_w, fr2_b, fr3_w, fr3_b,
                       fr1s_w, fr1s_b, fr2s_w, fr2s_b, fr3s_w, fr3s_b,
                       fo1_w, fo1_b, fo2_w, fo2_b, fo3_w, fo3_b, fcf_w, fcf_b,
                       (float*)d_out);
}